// Round 8
// baseline (172.632 us; speedup 1.0000x reference)
//
#include <hip/hip_runtime.h>
#include <hip/hip_bf16.h>

#define D_DIM 1024
#define S_DIM 2048
#define B_DIM 4
#define KTAPS 16

typedef short bf16x8 __attribute__((ext_vector_type(8)));
typedef float f32x4 __attribute__((ext_vector_type(4)));

// async global->LDS, 16B per lane (global_load_lds_dwordx4)
#define GLOAD16(gptr, lptr) \
  __builtin_amdgcn_global_load_lds((const __attribute__((address_space(1))) unsigned int*)(gptr), \
                                   (__attribute__((address_space(3))) unsigned int*)(lptr), 16, 0, 0)

// s_waitcnt immediates (gfx9: vm[3:0]=b0-3, exp=b4-6, lgkm=b8-11, vm[5:4]=b14-15)
#define WAIT_VM0 0x0F70   // vmcnt(0), lgkm/exp no-wait

static __device__ __forceinline__ short f2bs(float f) {
  __hip_bfloat16 h = __float2bfloat16(f);
  return *reinterpret_cast<short*>(&h);
}
static __device__ __forceinline__ float bs2f(short s) {
  unsigned int u = ((unsigned int)(unsigned short)s) << 16;
  return __builtin_bit_cast(float, u);
}

// ---------------------------------------------------------------------------
// Kernel 1 (merged setup): blocks [0,4096) write Wb in MFMA B-FRAGMENT ORDER;
// blocks [4096,4160) compute impulse response g_k[d] = C_d.A_d^k.B_d.
// Frag layout: flat index f -> block b=f>>9 (n-panel p=b>>5, k0=b&31),
// lane=(f>>3)&63, j=f&7;  n = p*16 + (lane&15), k = k0*32 + (lane>>4)*8 + j.
// A wave's B-fragment load is then ONE coalesced 16B/lane global load.
// ---------------------------------------------------------------------------
__global__ void setup_kernel(const float* __restrict__ W, __hip_bfloat16* __restrict__ Wbf,
                             const float* __restrict__ A, const float* __restrict__ Bm,
                             const float* __restrict__ Cm, const float* __restrict__ Dm,
                             float* __restrict__ gT) {
  if (blockIdx.x < 4096) {
    const int f    = blockIdx.x * 256 + threadIdx.x;
    const int p    = f >> 14;            // n-panel (0..63)
    const int k0   = (f >> 9) & 31;      // 32-wide k block
    const int lane = (f >> 3) & 63;
    const int j    = f & 7;
    const int n    = p * 16 + (lane & 15);
    const int k    = k0 * 32 + (lane >> 4) * 8 + j;
    Wbf[f] = __float2bfloat16(W[n * D_DIM + k]);
    return;
  }
  const int gb   = blockIdx.x - 4096;  // 0..63
  const int wid  = threadIdx.x >> 6;   // 0..3
  const int lane = threadIdx.x & 63;
  const int sub  = lane >> 4;          // 0..3 (channel within wave)
  const int n    = lane & 15;          // state index
  const int d    = gb * 16 + wid * 4 + sub;
  float Ar[16];
#pragma unroll
  for (int m = 0; m < 16; ++m) Ar[m] = A[d * 256 + n * 16 + m];
  float v = Bm[d * 16 + n];
  const float c   = Cm[d * 16 + n];
  const float dmv = Dm[d];
  const int base  = sub << 4;
  for (int k = 0; k < KTAPS; ++k) {
    float dot = c * v;
    dot += __shfl_xor(dot, 1);
    dot += __shfl_xor(dot, 2);
    dot += __shfl_xor(dot, 4);
    dot += __shfl_xor(dot, 8);
    if (k == 0) dot += dmv;            // fold the D x_t skip term into tap 0
    if (n == 0) gT[k * D_DIM + d] = dot;
    float nv = 0.f;
#pragma unroll
    for (int m = 0; m < 16; ++m) nv = fmaf(Ar[m], __shfl(v, base + m), nv);
    v = nv;
  }
}

// ---------------------------------------------------------------------------
// Kernel 2: depthwise causal conv, 16 taps, y emitted in bf16. Block =
// (b, 64-row chunk, 256-channel group), 512 blocks.
// ---------------------------------------------------------------------------
__global__ __launch_bounds__(256, 4) void conv_kernel(const float* __restrict__ x,
                                                      const float* __restrict__ gT,
                                                      __hip_bfloat16* __restrict__ y) {
  const int bx    = blockIdx.x;        // 512 blocks: b(4) x chunk(32) x dg(4)
  const int b     = bx >> 7;
  const int rem   = bx & 127;
  const int chunk = rem >> 2;          // 0..31
  const int dg    = rem & 3;
  const int d     = dg * 256 + threadIdx.x;
  const int s0    = chunk * 64;
  const float* xb = x + b * (S_DIM * D_DIM) + d;
  short* yb       = (short*)y + b * (S_DIM * D_DIM) + d;

  float g[KTAPS];
#pragma unroll
  for (int k = 0; k < KTAPS; ++k) g[k] = gT[k * D_DIM + d];

  float hist[16];                      // x[s - 16 .. s - 1]
#pragma unroll
  for (int i = 0; i < 16; ++i) {
    int s = s0 - 16 + i;
    hist[i] = (s >= 0) ? xb[s * D_DIM] : 0.0f;
  }

  for (int t = 0; t < 4; ++t) {        // 4 sub-tiles of 16 outputs
    const int sb = s0 + t * 16;
    float cur[16];
#pragma unroll
    for (int i = 0; i < 16; ++i) cur[i] = xb[(sb + i) * D_DIM];
#pragma unroll
    for (int j = 0; j < 16; ++j) {
      float acc = 0.f;
#pragma unroll
      for (int k = 0; k < KTAPS; ++k) {
        const int idx = j - k;          // compile-time constant
        const float xv = (idx >= 0) ? cur[idx] : hist[16 + idx];
        acc = fmaf(g[k], xv, acc);
      }
      yb[(sb + j) * D_DIM] = f2bs(acc);
    }
#pragma unroll
    for (int i = 0; i < 16; ++i) hist[i] = cur[i];
  }
}

// ---------------------------------------------------------------------------
// Kernel 3: LayerNorm(D=1024) + exact GELU, bf16 in -> bf16 out. Block per
// row; thread handles 4 contiguous channels.
// ---------------------------------------------------------------------------
__global__ __launch_bounds__(256) void ln_gelu_kernel(const __hip_bfloat16* __restrict__ y,
                                                      const float* __restrict__ w,
                                                      const float* __restrict__ bsh,
                                                      __hip_bfloat16* __restrict__ act) {
  __shared__ float red0[4];
  __shared__ float red1[4];
  const int row = blockIdx.x;
  const int tid = threadIdx.x;
  const int lane = tid & 63, wid = tid >> 6;
  const int d0 = tid * 4;

  const short4 s4 = *(const short4*)((const short*)y + (size_t)row * D_DIM + d0);
  float v[4] = {bs2f(s4.x), bs2f(s4.y), bs2f(s4.z), bs2f(s4.w)};

  float s = v[0] + v[1] + v[2] + v[3];
  s += __shfl_xor(s, 1);  s += __shfl_xor(s, 2);  s += __shfl_xor(s, 4);
  s += __shfl_xor(s, 8);  s += __shfl_xor(s, 16); s += __shfl_xor(s, 32);
  if (lane == 0) red0[wid] = s;
  __syncthreads();
  const float mu = (red0[0] + red0[1] + red0[2] + red0[3]) * (1.0f / D_DIM);

  float sq = 0.f;
#pragma unroll
  for (int j = 0; j < 4; ++j) { float t = v[j] - mu; sq = fmaf(t, t, sq); }
  sq += __shfl_xor(sq, 1);  sq += __shfl_xor(sq, 2);  sq += __shfl_xor(sq, 4);
  sq += __shfl_xor(sq, 8);  sq += __shfl_xor(sq, 16); sq += __shfl_xor(sq, 32);
  if (lane == 0) red1[wid] = sq;
  __syncthreads();
  const float var = (red1[0] + red1[1] + red1[2] + red1[3]) * (1.0f / D_DIM);
  const float inv = rsqrtf(var + 1e-5f);

  const float4 w4 = *(const float4*)&w[d0];
  const float4 b4 = *(const float4*)&bsh[d0];
  const float wv[4] = {w4.x, w4.y, w4.z, w4.w};
  const float bv[4] = {b4.x, b4.y, b4.z, b4.w};
  short4 o;
  short* op = &o.x;
#pragma unroll
  for (int j = 0; j < 4; ++j) {
    float t = (v[j] - mu) * inv * wv[j] + bv[j];
    float ge = 0.5f * t * (1.f + erff(t * 0.70710678118654752f));  // exact gelu
    op[j] = f2bs(ge);
  }
  *(short4*)((short*)act + (size_t)row * D_DIM + d0) = o;
}

// ---------------------------------------------------------------------------
// Kernel 4: out = x + Act @ W^T + b_out.  Hybrid-port MFMA GEMM:
//  - A (Act) staged via double-buffered LDS (XOR-swizzled, raw s_barrier,
//    BK=128, 2 x 32 KB) -> LDS read port.
//  - B (Wbf) loaded DIRECTLY from global in fragment order (one coalesced
//    16B/lane load per fragment, L2-resident 2 MB) -> VMEM port, no sync.
// This halves LDS traffic and barrier payload vs all-LDS; the two operand
// streams use independent ports. 4 waves (2x2), wave = 64x64 via 4x4 MFMA.
// C/D: col = lane&15, row = (lane>>4)*4 + reg.
// ---------------------------------------------------------------------------
__global__ __launch_bounds__(256, 2) void gemm_kernel(const __hip_bfloat16* __restrict__ Act,
                                                      const __hip_bfloat16* __restrict__ Wbf,
                                                      const float* __restrict__ x,
                                                      const float* __restrict__ bout,
                                                      float* __restrict__ out) {
  __shared__ short Al[2][128 * 128];  // 2 x 32 KB, A only
  const int tid  = threadIdx.x;
  const int lane = tid & 63;
  const int wave = tid >> 6;
  const int mBase = blockIdx.x * 128;
  const int nBase = blockIdx.y * 128;
  const int wm = (wave & 1) * 64;
  const int wn = (wave >> 1) * 64;
  const int l16 = lane & 15;
  const int kq  = lane >> 4;          // 0..3 k-quad

  // A staging: thread t -> row (tid>>4) (+16/round, 8 rounds); 16 chunks/row,
  // LDS slot (tid&15) <=> global chunk slot^(row&7)
  const int srow = tid >> 4;                       // 0..15
  const int cg   = (tid & 15) ^ (srow & 7);        // global 16B chunk fetched
  const short* Ag = (const short*)Act + (mBase + srow) * D_DIM + cg * 8;

  // B fragment base: panel pn = (nBase + wn)/16 + nt, k0_32 = it*4 + kki
  const short* Bf = (const short*)Wbf + lane * 8;

  f32x4 acc[4][4];
#pragma unroll
  for (int mt = 0; mt < 4; ++mt)
#pragma unroll
    for (int nt = 0; nt < 4; ++nt) acc[mt][nt] = (f32x4){0.f, 0.f, 0.f, 0.f};

  // prologue: stage A tile 0 into buffer 0
#pragma unroll
  for (int r = 0; r < 8; ++r)
    GLOAD16(Ag + r * 16 * D_DIM, &Al[0][tid * 8 + r * 2048]);

  const int pnW = (nBase + wn) >> 4;   // wave's first n-panel index

  for (int it = 0; it < 8; ++it) {
    const int cur = it & 1;
    __builtin_amdgcn_s_waitcnt(WAIT_VM0);   // cur A-tile DMA done (overlapped)
    __builtin_amdgcn_s_barrier();           // visible to all; buf^1 free (WAR)
    if (it < 7) {
      const int k1 = (it + 1) * 128;
#pragma unroll
      for (int r = 0; r < 8; ++r)
        GLOAD16(Ag + r * 16 * D_DIM + k1, &Al[cur ^ 1][tid * 8 + r * 2048]);
    }
    const short* Ab = Al[cur];
#pragma unroll
    for (int kki = 0; kki < 4; ++kki) {      // 4 x 32-wide k sub-steps
      const int kk = kki * 32;
      const int k0_32 = it * 4 + kki;        // global 32-wide k index
      bf16x8 af[4], bfr[4];
#pragma unroll
      for (int nt = 0; nt < 4; ++nt)         // direct global B-frag loads (L2)
        bfr[nt] = *(const bf16x8*)(Bf + (((size_t)(pnW + nt) * 32 + k0_32) << 9));
      const int cgr = (kk >> 3) + kq;        // global chunk this A-frag needs
#pragma unroll
      for (int mt = 0; mt < 4; ++mt) {
        const int r = wm + mt * 16 + l16;
        af[mt] = *(const bf16x8*)&Ab[r * 128 + ((cgr ^ (r & 7)) << 3)];
      }
#pragma unroll
      for (int mt = 0; mt < 4; ++mt)
#pragma unroll
        for (int nt = 0; nt < 4; ++nt)
          acc[mt][nt] = __builtin_amdgcn_mfma_f32_16x16x32_bf16(af[mt], bfr[nt], acc[mt][nt], 0, 0, 0);
    }
  }

  const int r0 = kq * 4;
#pragma unroll
  for (int mt = 0; mt < 4; ++mt) {
    const int row = mBase + wm + mt * 16 + r0;
#pragma unroll
    for (int nt = 0; nt < 4; ++nt) {
      const int col = nBase + wn + nt * 16 + l16;
      const float bo = bout[col];
#pragma unroll
      for (int r = 0; r < 4; ++r) {
        const int idx = (row + r) * D_DIM + col;
        out[idx] = x[idx] + acc[mt][nt][r] + bo;
      }
    }
  }
}

// ---------------------------------------------------------------------------
extern "C" void kernel_launch(void* const* d_in, const int* in_sizes, int n_in,
                              void* d_out, int out_size, void* d_ws, size_t ws_size,
                              hipStream_t stream) {
  const float* x    = (const float*)d_in[0];
  const float* A    = (const float*)d_in[1];
  const float* Bm   = (const float*)d_in[2];
  const float* Cm   = (const float*)d_in[3];
  const float* Dm   = (const float*)d_in[4];
  const float* lnw  = (const float*)d_in[5];
  const float* lnb  = (const float*)d_in[6];
  const float* Wout = (const float*)d_in[7];
  const float* bout = (const float*)d_in[8];
  float* out = (float*)d_out;

  char* ws = (char*)d_ws;
  float* gT            = (float*)ws;                        // 16*1024*4   = 64 KB
  __hip_bfloat16* Wbf  = (__hip_bfloat16*)(ws + 262144);    // 1024*1024*2 = 2 MB (frag order)
  __hip_bfloat16* Act  = (__hip_bfloat16*)(ws + 2359296);   // 8192*1024*2 = 16.75 MB
  __hip_bfloat16* ybf  = (__hip_bfloat16*)(ws + 19136512);  // 8192*1024*2 = 16.75 MB

  setup_kernel<<<4160, 256, 0, stream>>>(Wout, Wbf, A, Bm, Cm, Dm, gT);
  conv_kernel<<<512, 256, 0, stream>>>(x, gT, ybf);
  ln_gelu_kernel<<<8192, 256, 0, stream>>>(ybf, lnw, lnb, Act);
  gemm_kernel<<<dim3(64, 8), 256, 0, stream>>>(Act, Wbf, x, bout, out);
}